// Round 1
// baseline (212.334 us; speedup 1.0000x reference)
//
#include <hip/hip_runtime.h>

// Graph2Col: stable stream compaction of (m=128, V=2048, R=32) int32 mapping.
// Valid (!= -1) entries first in row-major order; tail filled with -1.
// Output layout in d_out (int32): nodes_indices [total*2] then column_indices [total*3].

#define EMPTY_V (-1)

constexpr int M_DIM = 128;
constexpr int V_DIM = 2048;
constexpr int R_DIM = 32;
constexpr int TOTAL = M_DIM * V_DIM * R_DIM;   // 8,388,608
constexpr int BLOCK = 256;
constexpr int CHUNK = 8192;                    // elements per block
constexpr int NB = TOTAL / CHUNK;              // 1024 blocks
constexpr int SUBT = CHUNK / (BLOCK * 4);      // 8 sub-tiles of 1024 elements
constexpr int NWAVE = BLOCK / 64;              // 4 waves per block

// ---------------------------------------------------------------- count pass
__global__ __launch_bounds__(BLOCK) void k_count(const int* __restrict__ in,
                                                 int* __restrict__ counts) {
    const int b = blockIdx.x;
    const int tid = threadIdx.x;
    const int4* p = (const int4*)(in + (size_t)b * CHUNK);
    int c = 0;
#pragma unroll
    for (int s = 0; s < SUBT; ++s) {
        int4 v = p[s * BLOCK + tid];
        c += (v.x != EMPTY_V) + (v.y != EMPTY_V) + (v.z != EMPTY_V) + (v.w != EMPTY_V);
    }
    // wave reduce (64 lanes)
    for (int d = 32; d > 0; d >>= 1) c += __shfl_down(c, d, 64);
    __shared__ int ws[NWAVE];
    const int lane = tid & 63, wid = tid >> 6;
    if (lane == 0) ws[wid] = c;
    __syncthreads();
    if (tid == 0) {
        int t = 0;
        for (int w = 0; w < NWAVE; ++w) t += ws[w];
        counts[b] = t;
    }
}

// ----------------------------------------------------- scan over block counts
__global__ __launch_bounds__(NB) void k_scan(const int* __restrict__ counts,
                                             int* __restrict__ offsets,
                                             int* __restrict__ total_valid) {
    const int tid = threadIdx.x;
    const int lane = tid & 63, wid = tid >> 6;
    int c = counts[tid];
    int incl = c;
    for (int d = 1; d < 64; d <<= 1) {
        int y = __shfl_up(incl, d, 64);
        if (lane >= d) incl += y;
    }
    __shared__ int ws[NB / 64];
    if (lane == 63) ws[wid] = incl;
    __syncthreads();
    int woff = 0;
    for (int w = 0; w < wid; ++w) woff += ws[w];
    offsets[tid] = woff + incl - c;
    if (tid == NB - 1) *total_valid = woff + incl;
}

// ------------------------------------------------------------- scatter pass
__global__ __launch_bounds__(BLOCK) void k_scatter(const int* __restrict__ in,
                                                   const int* __restrict__ offsets,
                                                   int* __restrict__ out_nodes,
                                                   int* __restrict__ out_cols) {
    const int b = blockIdx.x;
    const int tid = threadIdx.x;
    const int lane = tid & 63, wid = tid >> 6;
    const unsigned long long below = (lane == 0) ? 0ull : ((~0ull) >> (64 - lane));
    __shared__ int wsum[SUBT][NWAVE];
    int running = offsets[b];
    const int4* p = (const int4*)(in + (size_t)b * CHUNK);
#pragma unroll
    for (int s = 0; s < SUBT; ++s) {
        int4 v = p[s * BLOCK + tid];
        const int f0 = (v.x != EMPTY_V), f1 = (v.y != EMPTY_V);
        const int f2 = (v.z != EMPTY_V), f3 = (v.w != EMPTY_V);
        const unsigned long long b0 = __ballot(f0), b1 = __ballot(f1);
        const unsigned long long b2 = __ballot(f2), b3 = __ballot(f3);
        const int pre = __popcll(b0 & below) + __popcll(b1 & below) +
                        __popcll(b2 & below) + __popcll(b3 & below);
        const int wtot = __popcll(b0) + __popcll(b1) + __popcll(b2) + __popcll(b3);
        if (lane == 0) wsum[s][wid] = wtot;
        __syncthreads();
        int woff = 0, stot = 0;
        for (int w = 0; w < NWAVE; ++w) {
            const int x = wsum[s][w];
            stot += x;
            if (w < wid) woff += x;
        }
        int pos = running + woff + pre;
        const int i0 = b * CHUNK + s * (BLOCK * 4) + tid * 4;  // flat idx of v.x
        const int vals[4] = {v.x, v.y, v.z, v.w};
#pragma unroll
        for (int j = 0; j < 4; ++j) {
            if (vals[j] != EMPTY_V) {
                const int fi = i0 + j;
                const int row = fi >> 16;        // / (V*R) = 65536
                const int rem = fi & 65535;
                const int vert = rem >> 5;       // / R = 32
                const int reg = rem & 31;
                out_nodes[2 * pos]     = row;
                out_nodes[2 * pos + 1] = vals[j];
                out_cols[3 * pos]      = row;
                out_cols[3 * pos + 1]  = vert;
                out_cols[3 * pos + 2]  = reg;
                ++pos;
            }
        }
        running += stot;
        // no second barrier needed: next iteration uses disjoint wsum[s+1][*]
    }
}

// ------------------------------------------------------------- tail fill (-1)
__global__ __launch_bounds__(BLOCK) void k_tail(const int* __restrict__ total_valid,
                                                int* __restrict__ out_nodes,
                                                int* __restrict__ out_cols) {
    const int tv = *total_valid;
    const int stride = gridDim.x * blockDim.x;
    for (int pos = tv + blockIdx.x * blockDim.x + threadIdx.x; pos < TOTAL;
         pos += stride) {
        out_nodes[2 * pos]     = EMPTY_V;
        out_nodes[2 * pos + 1] = EMPTY_V;
        out_cols[3 * pos]      = EMPTY_V;
        out_cols[3 * pos + 1]  = EMPTY_V;
        out_cols[3 * pos + 2]  = EMPTY_V;
    }
}

extern "C" void kernel_launch(void* const* d_in, const int* in_sizes, int n_in,
                              void* d_out, int out_size, void* d_ws, size_t ws_size,
                              hipStream_t stream) {
    const int* in = (const int*)d_in[0];
    int* out = (int*)d_out;
    int* out_nodes = out;                    // [TOTAL, 2] int32
    int* out_cols = out + 2 * (size_t)TOTAL; // [TOTAL, 3] int32
    int* ws = (int*)d_ws;
    int* counts = ws;            // [NB]
    int* offsets = ws + NB;      // [NB]
    int* tv = ws + 2 * NB;       // [1]

    k_count<<<NB, BLOCK, 0, stream>>>(in, counts);
    k_scan<<<1, NB, 0, stream>>>(counts, offsets, tv);
    k_scatter<<<NB, BLOCK, 0, stream>>>(in, offsets, out_nodes, out_cols);
    k_tail<<<512, BLOCK, 0, stream>>>(tv, out_nodes, out_cols);
}

// Round 2
// 196.699 us; speedup vs baseline: 1.0795x; 1.0795x over previous
//
#include <hip/hip_runtime.h>

// Graph2Col: stable stream compaction of (m=128, V=2048, R=32) int32 mapping.
// Valid (!= -1) entries first in row-major order; tail filled with -1.
// Output layout in d_out (int32): nodes_indices [total*2] then column_indices [total*3].
//
// R2: scatter writes staged through LDS (SoA val/pos), streamed out coalesced.
//     row is block-constant (b>>3); vert/reg recovered from packed pos (fi&65535).

#define EMPTY_V (-1)

constexpr int M_DIM = 128;
constexpr int V_DIM = 2048;
constexpr int R_DIM = 32;
constexpr int TOTAL = M_DIM * V_DIM * R_DIM;   // 8,388,608
constexpr int BLOCK = 256;
constexpr int CHUNK = 8192;                    // elements per block
constexpr int NB = TOTAL / CHUNK;              // 1024 blocks
constexpr int SUBT = CHUNK / (BLOCK * 4);      // 8 sub-tiles of 1024 elements
constexpr int NWAVE = BLOCK / 64;              // 4 waves per block
constexpr int STAGE = BLOCK * 4;               // 1024 entries staged per sub-tile

// ---------------------------------------------------------------- count pass
__global__ __launch_bounds__(BLOCK) void k_count(const int* __restrict__ in,
                                                 int* __restrict__ counts) {
    const int b = blockIdx.x;
    const int tid = threadIdx.x;
    const int4* p = (const int4*)(in + (size_t)b * CHUNK);
    int c = 0;
#pragma unroll
    for (int s = 0; s < SUBT; ++s) {
        int4 v = p[s * BLOCK + tid];
        c += (v.x != EMPTY_V) + (v.y != EMPTY_V) + (v.z != EMPTY_V) + (v.w != EMPTY_V);
    }
    for (int d = 32; d > 0; d >>= 1) c += __shfl_down(c, d, 64);
    __shared__ int ws[NWAVE];
    const int lane = tid & 63, wid = tid >> 6;
    if (lane == 0) ws[wid] = c;
    __syncthreads();
    if (tid == 0) {
        int t = 0;
        for (int w = 0; w < NWAVE; ++w) t += ws[w];
        counts[b] = t;
    }
}

// ----------------------------------------------------- scan over block counts
__global__ __launch_bounds__(NB) void k_scan(const int* __restrict__ counts,
                                             int* __restrict__ offsets,
                                             int* __restrict__ total_valid) {
    const int tid = threadIdx.x;
    const int lane = tid & 63, wid = tid >> 6;
    int c = counts[tid];
    int incl = c;
    for (int d = 1; d < 64; d <<= 1) {
        int y = __shfl_up(incl, d, 64);
        if (lane >= d) incl += y;
    }
    __shared__ int ws[NB / 64];
    if (lane == 63) ws[wid] = incl;
    __syncthreads();
    int woff = 0;
    for (int w = 0; w < wid; ++w) woff += ws[w];
    offsets[tid] = woff + incl - c;
    if (tid == NB - 1) *total_valid = woff + incl;
}

// ------------------------------------------------------------- scatter pass
__global__ __launch_bounds__(BLOCK) void k_scatter(const int* __restrict__ in,
                                                   const int* __restrict__ offsets,
                                                   int* __restrict__ out_nodes,
                                                   int* __restrict__ out_cols) {
    const int b = blockIdx.x;
    const int tid = threadIdx.x;
    const int lane = tid & 63, wid = tid >> 6;
    const unsigned long long below = lane ? ((~0ull) >> (64 - lane)) : 0ull;
    __shared__ int wsum[NWAVE];
    __shared__ int s_val[STAGE];
    __shared__ int s_pos[STAGE];   // fi & 65535 (packs vert<<5 | reg)
    const int row = b >> 3;        // 8192 elems/block, 65536 elems/output-row
    int running = offsets[b];
    const int4* p = (const int4*)(in + (size_t)b * CHUNK);
#pragma unroll 1
    for (int s = 0; s < SUBT; ++s) {
        const int4 v = p[s * BLOCK + tid];
        const int f0 = (v.x != EMPTY_V), f1 = (v.y != EMPTY_V);
        const int f2 = (v.z != EMPTY_V), f3 = (v.w != EMPTY_V);
        const unsigned long long b0 = __ballot(f0), b1 = __ballot(f1);
        const unsigned long long b2 = __ballot(f2), b3 = __ballot(f3);
        const int pre = __popcll(b0 & below) + __popcll(b1 & below) +
                        __popcll(b2 & below) + __popcll(b3 & below);
        const int wtot = __popcll(b0) + __popcll(b1) + __popcll(b2) + __popcll(b3);
        if (lane == 0) wsum[wid] = wtot;
        __syncthreads();
        int woff = 0, cnt = 0;
        for (int w = 0; w < NWAVE; ++w) {
            const int x = wsum[w];
            cnt += x;
            if (w < wid) woff += x;
        }
        int lp = woff + pre;  // local rank within this sub-tile's compacted window
        const int rem0 = ((b & 7) << 13) + (s << 10) + (tid << 2);  // fi & 65535, j=0
        const int vals[4] = {v.x, v.y, v.z, v.w};
        const int fl[4] = {f0, f1, f2, f3};
#pragma unroll
        for (int j = 0; j < 4; ++j) {
            if (fl[j]) { s_val[lp] = vals[j]; s_pos[lp] = rem0 + j; ++lp; }
        }
        __syncthreads();
        // ---- coalesced writeout of this sub-tile's window [running, running+cnt)
        int2* ndst2 = (int2*)(out_nodes + 2 * (size_t)running);  // 8B-aligned
        for (int k = tid; k < cnt; k += BLOCK) {
            ndst2[k] = make_int2(row, s_val[k]);
        }
        int* cdst = out_cols + 3 * (size_t)running;
        const int cdw = 3 * cnt;
        for (int d = tid; d < cdw; d += BLOCK) {
            const int e = d / 3;           // magic-mul
            const int r = d - 3 * e;
            int val = row;
            if (r != 0) {
                const int pp = s_pos[e];
                val = (r == 1) ? (pp >> 5) : (pp & 31);
            }
            cdst[d] = val;
        }
        running += cnt;
        __syncthreads();  // protect wsum/s_val/s_pos for next sub-tile
    }
}

// ------------------------------------------------------------- tail fill (-1)
__global__ __launch_bounds__(BLOCK) void k_tail(const int* __restrict__ total_valid,
                                                int* __restrict__ out_nodes,
                                                int* __restrict__ out_cols) {
    const int tv = *total_valid;
    const int stride = gridDim.x * blockDim.x;
    for (int pos = tv + blockIdx.x * blockDim.x + threadIdx.x; pos < TOTAL;
         pos += stride) {
        out_nodes[2 * pos]     = EMPTY_V;
        out_nodes[2 * pos + 1] = EMPTY_V;
        out_cols[3 * pos]      = EMPTY_V;
        out_cols[3 * pos + 1]  = EMPTY_V;
        out_cols[3 * pos + 2]  = EMPTY_V;
    }
}

extern "C" void kernel_launch(void* const* d_in, const int* in_sizes, int n_in,
                              void* d_out, int out_size, void* d_ws, size_t ws_size,
                              hipStream_t stream) {
    const int* in = (const int*)d_in[0];
    int* out = (int*)d_out;
    int* out_nodes = out;                    // [TOTAL, 2] int32
    int* out_cols = out + 2 * (size_t)TOTAL; // [TOTAL, 3] int32
    int* ws = (int*)d_ws;
    int* counts = ws;            // [NB]
    int* offsets = ws + NB;      // [NB]
    int* tv = ws + 2 * NB;       // [1]

    k_count<<<NB, BLOCK, 0, stream>>>(in, counts);
    k_scan<<<1, NB, 0, stream>>>(counts, offsets, tv);
    k_scatter<<<NB, BLOCK, 0, stream>>>(in, offsets, out_nodes, out_cols);
    k_tail<<<512, BLOCK, 0, stream>>>(tv, out_nodes, out_cols);
}

// Round 3
// 191.964 us; speedup vs baseline: 1.1061x; 1.0247x over previous
//
#include <hip/hip_runtime.h>

// Graph2Col: stable stream compaction of (m=128, V=2048, R=32) int32 mapping.
// Valid (!= -1) entries first in row-major order; tail filled with -1.
// Output layout in d_out (int32): nodes_indices [total*2] then column_indices [total*3].
//
// R3: 2 kernels only. Scatter blocks redundantly scan counts[] (L2-hot, no
//     separate scan kernel), tail fill fused into scatter epilogue. Writeout
//     uses int4 stores with alignment peel.

#define EMPTY_V (-1)

constexpr int M_DIM = 128;
constexpr int V_DIM = 2048;
constexpr int R_DIM = 32;
constexpr int TOTAL = M_DIM * V_DIM * R_DIM;   // 8,388,608
constexpr int BLOCK = 256;
constexpr int CHUNK = 8192;                    // elements per block
constexpr int NB = TOTAL / CHUNK;              // 1024 blocks
constexpr int SUBT = CHUNK / (BLOCK * 4);      // 8 sub-tiles of 1024 elements
constexpr int NWAVE = BLOCK / 64;              // 4 waves per block
constexpr int STAGE = BLOCK * 4;               // 1024 entries staged per sub-tile

// ---------------------------------------------------------------- count pass
__global__ __launch_bounds__(BLOCK) void k_count(const int* __restrict__ in,
                                                 int* __restrict__ counts) {
    const int b = blockIdx.x;
    const int tid = threadIdx.x;
    const int4* p = (const int4*)(in + (size_t)b * CHUNK);
    int c = 0;
#pragma unroll
    for (int s = 0; s < SUBT; ++s) {
        int4 v = p[s * BLOCK + tid];
        c += (v.x != EMPTY_V) + (v.y != EMPTY_V) + (v.z != EMPTY_V) + (v.w != EMPTY_V);
    }
    for (int d = 32; d > 0; d >>= 1) c += __shfl_down(c, d, 64);
    __shared__ int ws[NWAVE];
    const int lane = tid & 63, wid = tid >> 6;
    if (lane == 0) ws[wid] = c;
    __syncthreads();
    if (tid == 0) {
        int t = 0;
        for (int w = 0; w < NWAVE; ++w) t += ws[w];
        counts[b] = t;
    }
}

// -------------------------------------------- scatter pass (scan+tail fused)
__global__ __launch_bounds__(BLOCK) void k_scatter(const int* __restrict__ in,
                                                   const int* __restrict__ counts,
                                                   int* __restrict__ out_nodes,
                                                   int* __restrict__ out_cols) {
    const int b = blockIdx.x;
    const int tid = threadIdx.x;
    const int lane = tid & 63, wid = tid >> 6;
    const unsigned long long below = lane ? ((~0ull) >> (64 - lane)) : 0ull;

    // ---- redundant block-local scan of counts[NB]: exclusive prefix + total
    __shared__ int red[2 * NWAVE];
    {
        const int4 c4 = ((const int4*)counts)[tid];   // counts[4t..4t+3]
        const int idx0 = tid * 4;
        const int cs[4] = {c4.x, c4.y, c4.z, c4.w};
        int pa = 0, ta = 0;
#pragma unroll
        for (int j = 0; j < 4; ++j) {
            ta += cs[j];
            if (idx0 + j < b) pa += cs[j];
        }
        for (int d = 32; d > 0; d >>= 1) {
            pa += __shfl_down(pa, d, 64);
            ta += __shfl_down(ta, d, 64);
        }
        if (lane == 0) { red[wid] = pa; red[NWAVE + wid] = ta; }
    }
    __syncthreads();
    int running = 0, tv = 0;
    for (int w = 0; w < NWAVE; ++w) { running += red[w]; tv += red[NWAVE + w]; }

    __shared__ int wsum[NWAVE];
    __shared__ int s_val[STAGE];
    __shared__ int s_pos[STAGE];   // fi & 65535 (packs vert<<5 | reg)
    const int row = b >> 3;        // 8192 elems/block, 65536 elems/output-row
    const int4* p = (const int4*)(in + (size_t)b * CHUNK);
#pragma unroll 1
    for (int s = 0; s < SUBT; ++s) {
        const int4 v = p[s * BLOCK + tid];
        const int f0 = (v.x != EMPTY_V), f1 = (v.y != EMPTY_V);
        const int f2 = (v.z != EMPTY_V), f3 = (v.w != EMPTY_V);
        const unsigned long long b0 = __ballot(f0), b1 = __ballot(f1);
        const unsigned long long b2 = __ballot(f2), b3 = __ballot(f3);
        const int pre = __popcll(b0 & below) + __popcll(b1 & below) +
                        __popcll(b2 & below) + __popcll(b3 & below);
        const int wtot = __popcll(b0) + __popcll(b1) + __popcll(b2) + __popcll(b3);
        if (lane == 0) wsum[wid] = wtot;
        __syncthreads();
        int woff = 0, cnt = 0;
        for (int w = 0; w < NWAVE; ++w) {
            const int x = wsum[w];
            cnt += x;
            if (w < wid) woff += x;
        }
        int lp = woff + pre;  // local rank within this sub-tile's window
        const int rem0 = ((b & 7) << 13) + (s << 10) + (tid << 2);  // fi & 65535
        const int vals[4] = {v.x, v.y, v.z, v.w};
        const int fl[4] = {f0, f1, f2, f3};
#pragma unroll
        for (int j = 0; j < 4; ++j) {
            if (fl[j]) { s_val[lp] = vals[j]; s_pos[lp] = rem0 + j; ++lp; }
        }
        __syncthreads();

        // ---- nodes: int4 stores (2 entries each), peel for 16B alignment
        {
            int2* b2p = (int2*)out_nodes + running;           // 8B units
            const int head = ((running & 1) && cnt > 0) ? 1 : 0;
            if (head && tid == 0) b2p[0] = make_int2(row, s_val[0]);
            const int nPairs = (cnt - head) >> 1;
            int4* b4p = (int4*)(b2p + head);                  // 16B aligned
            for (int k = tid; k < nPairs; k += BLOCK) {
                const int e = head + 2 * k;
                b4p[k] = make_int4(row, s_val[e], row, s_val[e + 1]);
            }
            if (((cnt - head) & 1) && tid == BLOCK - 1)
                b2p[cnt - 1] = make_int2(row, s_val[cnt - 1]);
        }
        // ---- cols: int4 stores (4 dwords each), peel for 16B alignment
        {
            int* cd = out_cols + 3 * (size_t)running;
            const int cdw = 3 * cnt;
            const int mis = (3 * running) & 3;
            int peel = mis ? (4 - mis) : 0;
            if (peel > cdw) peel = cdw;
            if (tid < peel) {
                const int ld = tid;
                const int e = ld / 3, r = ld - 3 * e;
                int vv = row;
                if (r) { const int pp = s_pos[e]; vv = (r == 1) ? (pp >> 5) : (pp & 31); }
                cd[ld] = vv;
            }
            const int body = (cdw - peel) >> 2;
            int4* c4p = (int4*)(cd + peel);                   // 16B aligned
            for (int k = tid; k < body; k += BLOCK) {
                const int ld0 = peel + 4 * k;
                int vv[4];
#pragma unroll
                for (int i = 0; i < 4; ++i) {
                    const int ld = ld0 + i;
                    const int e = ld / 3, r = ld - 3 * e;
                    int x = row;
                    if (r) { const int pp = s_pos[e]; x = (r == 1) ? (pp >> 5) : (pp & 31); }
                    vv[i] = x;
                }
                c4p[k] = make_int4(vv[0], vv[1], vv[2], vv[3]);
            }
            const int tails = cdw - peel - 4 * body;
            if (tid < tails) {
                const int ld = peel + 4 * body + tid;
                const int e = ld / 3, r = ld - 3 * e;
                int vv = row;
                if (r) { const int pp = s_pos[e]; vv = (r == 1) ? (pp >> 5) : (pp & 31); }
                cd[ld] = vv;
            }
        }
        running += cnt;
        __syncthreads();  // protect wsum/s_val/s_pos for next sub-tile
    }

    // ---- fused tail fill: positions [tv, TOTAL) get -1 everywhere
    for (int pos = tv + b * BLOCK + tid; pos < TOTAL; pos += NB * BLOCK) {
        out_nodes[2 * pos]     = EMPTY_V;
        out_nodes[2 * pos + 1] = EMPTY_V;
        out_cols[3 * pos]      = EMPTY_V;
        out_cols[3 * pos + 1]  = EMPTY_V;
        out_cols[3 * pos + 2]  = EMPTY_V;
    }
}

extern "C" void kernel_launch(void* const* d_in, const int* in_sizes, int n_in,
                              void* d_out, int out_size, void* d_ws, size_t ws_size,
                              hipStream_t stream) {
    const int* in = (const int*)d_in[0];
    int* out = (int*)d_out;
    int* out_nodes = out;                    // [TOTAL, 2] int32
    int* out_cols = out + 2 * (size_t)TOTAL; // [TOTAL, 3] int32
    int* counts = (int*)d_ws;                // [NB]

    k_count<<<NB, BLOCK, 0, stream>>>(in, counts);
    k_scatter<<<NB, BLOCK, 0, stream>>>(in, counts, out_nodes, out_cols);
}